// Round 1
// baseline (66.967 us; speedup 1.0000x reference)
//
#include <hip/hip_runtime.h>
#include <hip/hip_bf16.h>

// Problem constants (from reference): B=8, N=4096, D=3
#define B_ 8
#define N_ 4096

__global__ void chamfer_init_acc(double* acc) {
    if (threadIdx.x < 2) acc[threadIdx.x] = 0.0;
}

// dir = blockIdx.z:
//   dir 0: own = y (index j), opp = x, mask = x_mask  -> acc[0]  (min over axis 1)
//   dir 1: own = x (index i), opp = y, mask = y_mask  -> acc[1]  (min over axis 2)
// Block: 256 threads = 4 waves. 64 own-points per block (lane l = t&63),
// wave s = t>>6 covers opposite indices [s*1024, (s+1)*1024).
__global__ __launch_bounds__(256) void chamfer_min_kernel(
        const float* __restrict__ x, const float* __restrict__ y,
        const float* __restrict__ xm, const float* __restrict__ ym,
        double* __restrict__ acc) {
    const int dir  = blockIdx.z;
    const int b    = blockIdx.y;
    const int base = blockIdx.x * 64;

    const float* own = dir ? x  : y;
    const float* opp = dir ? y  : x;
    const float* msk = dir ? ym : xm;

    __shared__ float sx[N_];
    __shared__ float sy[N_];
    __shared__ float sz[N_];
    __shared__ float red[4][64];

    const int t = threadIdx.x;

    // Stage full opposite set for batch b into LDS, SoA layout.
    const float* ob = opp + (size_t)b * N_ * 3;
    for (int f = t; f < N_ * 3; f += 256) {
        float v = ob[f];
        int i = f / 3;
        int c = f - 3 * i;
        if (c == 0)      sx[i] = v;
        else if (c == 1) sy[i] = v;
        else             sz[i] = v;
    }
    __syncthreads();

    const int l = t & 63;
    const int s = t >> 6;

    const float* op = own + ((size_t)b * N_ + base + l) * 3;
    const float px = op[0], py = op[1], pz = op[2];

    float m0 = 1e30f, m1 = 1e30f, m2 = 1e30f, m3 = 1e30f;

    const int k0 = s * (N_ / 4);
    const int k1 = k0 + (N_ / 4);

#define EVAL_(C, M) { float dx = xv.C - px; float dy = yv.C - py; float dz = zv.C - pz; \
                      float d = dx * dx + dy * dy + dz * dz; M = fminf(M, d); }

#pragma unroll 2
    for (int k = k0; k < k1; k += 4) {
        const float4 xv = *reinterpret_cast<const float4*>(&sx[k]);
        const float4 yv = *reinterpret_cast<const float4*>(&sy[k]);
        const float4 zv = *reinterpret_cast<const float4*>(&sz[k]);
        EVAL_(x, m0)
        EVAL_(y, m1)
        EVAL_(z, m2)
        EVAL_(w, m3)
    }
#undef EVAL_

    float mw = fminf(fminf(m0, m1), fminf(m2, m3));
    red[s][l] = mw;
    __syncthreads();

    if (t < 64) {
        float mn = fminf(fminf(red[0][t], red[1][t]), fminf(red[2][t], red[3][t]));
        float w  = msk[(size_t)b * N_ + base + t];
        double val = (double)(w * mn);
        // wave-level reduction across 64 lanes (f64)
        for (int off = 32; off; off >>= 1)
            val += __shfl_down(val, off);
        if (t == 0)
            atomicAdd(&acc[dir], val);
    }
}

__global__ void chamfer_finalize(const double* __restrict__ acc, float* __restrict__ out) {
    double d = (acc[0] - acc[1]) / (double)(B_ * N_);
    out[0] = (float)(d * d);
}

extern "C" void kernel_launch(void* const* d_in, const int* in_sizes, int n_in,
                              void* d_out, int out_size, void* d_ws, size_t ws_size,
                              hipStream_t stream) {
    const float* x  = (const float*)d_in[0];
    const float* y  = (const float*)d_in[1];
    const float* xm = (const float*)d_in[2];
    const float* ym = (const float*)d_in[3];
    float* out = (float*)d_out;
    double* acc = (double*)d_ws;   // 2 doubles of scratch

    chamfer_init_acc<<<1, 64, 0, stream>>>(acc);

    dim3 grid(N_ / 64, B_, 2);
    chamfer_min_kernel<<<grid, 256, 0, stream>>>(x, y, xm, ym, acc);

    chamfer_finalize<<<1, 1, 0, stream>>>(acc, out);
}